// Round 4
// baseline (588.723 us; speedup 1.0000x reference)
//
#include <hip/hip_runtime.h>
#include <cstdint>

#define BLOCK 256
#define UNROLL 4

typedef float f4 __attribute__((ext_vector_type(4)));  // native vec: nt-builtin OK

// Lane i loads float4 #i (fully coalesced). One element's 32 spike floats span
// 8 consecutive lanes (4/lane). Pack nibble pre-shifted into IEEE MSB-first
// position, OR-butterfly over xor 1,2,4, redundant fp32 multiply in all 8
// lanes, each lane unpacks its own 4 output bits -> coalesced nt store.
// UNROLL=4: all 8 loads issued before any use -> 4x bytes in flight per wave.
__global__ __launch_bounds__(BLOCK) void spikefp32mul_kernel(
    const f4* __restrict__ A4, const f4* __restrict__ B4,
    f4* __restrict__ O4)
{
    int g0 = blockIdx.x * (BLOCK * UNROLL) + threadIdx.x;

    f4 a[UNROLL], b[UNROLL];
#pragma unroll
    for (int k = 0; k < UNROLL; ++k) {
        a[k] = A4[g0 + k * BLOCK];
        b[k] = B4[g0 + k * BLOCK];
    }

    // g & 7 is the same for every iteration (stride BLOCK ≡ 0 mod 8).
    const int sb = 28 - 4 * (g0 & 7);

#pragma unroll
    for (int k = 0; k < UNROLL; ++k) {
        uint32_t wa = ((a[k].x > 0.5f ? 8u : 0u) | (a[k].y > 0.5f ? 4u : 0u) |
                       (a[k].z > 0.5f ? 2u : 0u) | (a[k].w > 0.5f ? 1u : 0u)) << sb;
        uint32_t wb = ((b[k].x > 0.5f ? 8u : 0u) | (b[k].y > 0.5f ? 4u : 0u) |
                       (b[k].z > 0.5f ? 2u : 0u) | (b[k].w > 0.5f ? 1u : 0u)) << sb;

        wa |= (uint32_t)__shfl_xor((int)wa, 1, 64);
        wb |= (uint32_t)__shfl_xor((int)wb, 1, 64);
        wa |= (uint32_t)__shfl_xor((int)wa, 2, 64);
        wb |= (uint32_t)__shfl_xor((int)wb, 2, 64);
        wa |= (uint32_t)__shfl_xor((int)wa, 4, 64);
        wb |= (uint32_t)__shfl_xor((int)wb, 4, 64);

        float p = __uint_as_float(wa) * __uint_as_float(wb);  // IEEE fp32, RNE
        uint32_t wp = __float_as_uint(p);

        f4 o;
        o.x = (float)((wp >> (sb + 3)) & 1u);
        o.y = (float)((wp >> (sb + 2)) & 1u);
        o.z = (float)((wp >> (sb + 1)) & 1u);
        o.w = (float)((wp >> sb) & 1u);
        __builtin_nontemporal_store(o, &O4[g0 + k * BLOCK]);
    }
}

// Tail safety (not used at this problem size: n4 divides exactly).
__global__ __launch_bounds__(BLOCK) void spikefp32mul_tail(
    const f4* __restrict__ A4, const f4* __restrict__ B4,
    f4* __restrict__ O4, int start, int n4)
{
    int g = start + blockIdx.x * blockDim.x + threadIdx.x;
    if (g >= n4) return;
    f4 a = A4[g], b = B4[g];
    const int sb = 28 - 4 * (g & 7);
    uint32_t wa = ((a.x > 0.5f ? 8u : 0u) | (a.y > 0.5f ? 4u : 0u) |
                   (a.z > 0.5f ? 2u : 0u) | (a.w > 0.5f ? 1u : 0u)) << sb;
    uint32_t wb = ((b.x > 0.5f ? 8u : 0u) | (b.y > 0.5f ? 4u : 0u) |
                   (b.z > 0.5f ? 2u : 0u) | (b.w > 0.5f ? 1u : 0u)) << sb;
    wa |= (uint32_t)__shfl_xor((int)wa, 1, 64);
    wb |= (uint32_t)__shfl_xor((int)wb, 1, 64);
    wa |= (uint32_t)__shfl_xor((int)wa, 2, 64);
    wb |= (uint32_t)__shfl_xor((int)wb, 2, 64);
    wa |= (uint32_t)__shfl_xor((int)wa, 4, 64);
    wb |= (uint32_t)__shfl_xor((int)wb, 4, 64);
    float p = __uint_as_float(wa) * __uint_as_float(wb);
    uint32_t wp = __float_as_uint(p);
    f4 o;
    o.x = (float)((wp >> (sb + 3)) & 1u);
    o.y = (float)((wp >> (sb + 2)) & 1u);
    o.z = (float)((wp >> (sb + 1)) & 1u);
    o.w = (float)((wp >> sb) & 1u);
    O4[g] = o;
}

extern "C" void kernel_launch(void* const* d_in, const int* in_sizes, int n_in,
                              void* d_out, int out_size, void* d_ws, size_t ws_size,
                              hipStream_t stream) {
    const f4* A4 = (const f4*)d_in[0];
    const f4* B4 = (const f4*)d_in[1];
    f4* O4 = (f4*)d_out;

    int n4 = in_sizes[0] / 4;                 // 16,777,216
    int per_block = BLOCK * UNROLL;           // 1024 float4s per block
    int grid = n4 / per_block;                // 16384, exact
    if (grid > 0)
        spikefp32mul_kernel<<<grid, BLOCK, 0, stream>>>(A4, B4, O4);
    int done = grid * per_block;
    int rem = n4 - done;
    if (rem > 0) {
        int tgrid = (rem + BLOCK - 1) / BLOCK;
        spikefp32mul_tail<<<tgrid, BLOCK, 0, stream>>>(A4, B4, O4, done, n4);
    }
}

// Round 5
// 577.134 us; speedup vs baseline: 1.0201x; 1.0201x over previous
//
#include <hip/hip_runtime.h>
#include <cstdint>

#define BLOCK 256
#define UNROLL 8

// Ballot/brev scheme, zero LDS traffic:
//   - dword loads: lane l of a wave holds float #(wavebase + l), wavebase % 64 == 0.
//   - __ballot(v > 0.5) : bit l = spike of lane l. Low 32 bits = element e0
//     (bit j = IEEE bit 31-j), high 32 = element e1. __brev() of each half IS
//     the packed IEEE word (wave-uniform, lives in SGPRs).
//   - each lane selects its half's word (v_cndmask), one v_mul_f32,
//     out bit = (wp >> ((~lane)&31)) & 1, cvt, coalesced dword store.
// UNROLL=8: 16 loads issued up front -> 4KB/wave in flight.
__global__ __launch_bounds__(BLOCK) void spikefp32mul_kernel(
    const float* __restrict__ A, const float* __restrict__ B,
    float* __restrict__ O)
{
    const int g0 = blockIdx.x * (BLOCK * UNROLL) + threadIdx.x;
    const int lane = threadIdx.x & 63;
    const int sh = (~lane) & 31;           // per-lane output bit shift
    const bool hi_half = (lane & 32) != 0;

    float a[UNROLL], b[UNROLL];
#pragma unroll
    for (int k = 0; k < UNROLL; ++k) {
        a[k] = A[g0 + k * BLOCK];
        b[k] = B[g0 + k * BLOCK];
    }

#pragma unroll
    for (int k = 0; k < UNROLL; ++k) {
        unsigned long long ba = __ballot(a[k] > 0.5f);
        unsigned long long bb = __ballot(b[k] > 0.5f);

        uint32_t wa_lo = __brev((uint32_t)ba);
        uint32_t wa_hi = __brev((uint32_t)(ba >> 32));
        uint32_t wb_lo = __brev((uint32_t)bb);
        uint32_t wb_hi = __brev((uint32_t)(bb >> 32));

        uint32_t wa = hi_half ? wa_hi : wa_lo;
        uint32_t wb = hi_half ? wb_hi : wb_lo;

        float p = __uint_as_float(wa) * __uint_as_float(wb);  // IEEE fp32, RNE
        uint32_t wp = __float_as_uint(p);

        O[g0 + k * BLOCK] = (float)((wp >> sh) & 1u);
    }
}

// Tail safety (not used at this problem size: n divides exactly).
__global__ __launch_bounds__(BLOCK) void spikefp32mul_tail(
    const float* __restrict__ A, const float* __restrict__ B,
    float* __restrict__ O, int start, int n)
{
    int g = start + blockIdx.x * blockDim.x + threadIdx.x;
    const int lane = threadIdx.x & 63;
    const int sh = (~lane) & 31;
    const bool hi_half = (lane & 32) != 0;
    bool act = g < n;
    float av = act ? A[g] : 0.0f;
    float bv = act ? B[g] : 0.0f;
    unsigned long long ba = __ballot(av > 0.5f);
    unsigned long long bb = __ballot(bv > 0.5f);
    uint32_t wa = hi_half ? __brev((uint32_t)(ba >> 32)) : __brev((uint32_t)ba);
    uint32_t wb = hi_half ? __brev((uint32_t)(bb >> 32)) : __brev((uint32_t)bb);
    float p = __uint_as_float(wa) * __uint_as_float(wb);
    uint32_t wp = __float_as_uint(p);
    if (act) O[g] = (float)((wp >> sh) & 1u);
}

extern "C" void kernel_launch(void* const* d_in, const int* in_sizes, int n_in,
                              void* d_out, int out_size, void* d_ws, size_t ws_size,
                              hipStream_t stream) {
    const float* A = (const float*)d_in[0];
    const float* B = (const float*)d_in[1];
    float* O = (float*)d_out;

    int n = in_sizes[0];                      // 67,108,864 floats
    int per_block = BLOCK * UNROLL;           // 2048 floats per block
    int grid = n / per_block;                 // 32768, exact
    if (grid > 0)
        spikefp32mul_kernel<<<grid, BLOCK, 0, stream>>>(A, B, O);
    int done = grid * per_block;
    int rem = n - done;
    if (rem > 0) {
        int tgrid = (rem + BLOCK - 1) / BLOCK;
        spikefp32mul_tail<<<tgrid, BLOCK, 0, stream>>>(A, B, O, done, n);
    }
}